// Round 4
// baseline (258.999 us; speedup 1.0000x reference)
//
#include <hip/hip_runtime.h>
#include <hip/hip_bf16.h>
#include <cstdint>
#include <cstddef>

typedef unsigned short u16;
typedef __attribute__((ext_vector_type(8))) short bf16x8;   // 8 bf16 = 4 VGPRs (MFMA A/B frag)
typedef __attribute__((ext_vector_type(4))) float f32x4;    // MFMA C/D frag
typedef __attribute__((ext_vector_type(4))) u16 u16x4;
typedef __attribute__((ext_vector_type(8))) u16 u16x8;
typedef __attribute__((ext_vector_type(4))) __bf16 bfx4;    // 4 native bf16 -> 2 v_cvt_pk_bf16_f32

#define AS1 __attribute__((address_space(1)))
#define AS3 __attribute__((address_space(3)))

// async global->LDS, 16B per lane; LDS dest must be wave-uniform base + lane*16
__device__ __forceinline__ void gl_lds16(const void* g, void* l) {
  __builtin_amdgcn_global_load_lds((const AS1 unsigned int*)g, (AS3 unsigned int*)l, 16, 0, 0);
}

__device__ __forceinline__ u16 f2bf(float f) {  // round-to-nearest-even bf16 (cold paths)
  union { float f; unsigned u; } v; v.f = f;
  unsigned r = v.u + 0x7FFFu + ((v.u >> 16) & 1u);
  return (u16)(r >> 16);
}

__device__ __forceinline__ float bf2f(u16 b) {
  union { float f; unsigned u; } v; v.u = ((unsigned)b) << 16; return v.f;
}

__device__ __forceinline__ float fast_exp2(float x) {  // v_exp_f32 = exact hw exp2
  float r; asm("v_exp_f32 %0, %1" : "=v"(r) : "v"(x)); return r;
}

#define NEGINF (-__builtin_inff())
#define LOG2E 1.44269504088896340736f
#define RESCALE_THR 7.0f

// ---------------- fp32 -> bf16 convert (x) ----------------
__global__ __launch_bounds__(256) void conv_x_kernel(const float* __restrict__ x, u16* __restrict__ xb) {
  int i = blockIdx.x * 256 + threadIdx.x;   // 1M threads, 4 elements each
  float4 v = ((const float4*)x)[i];
  u16x4 o;
  o[0] = f2bf(v.x); o[1] = f2bf(v.y); o[2] = f2bf(v.z); o[3] = f2bf(v.w);
  ((u16x4*)xb)[i] = o;
}

// -------- weight transpose+convert: W[K][N] f32 -> Wt[N][K] bf16 (4 weights) --------
__global__ __launch_bounds__(256) void conv_w_kernel(const float* __restrict__ wq, const float* __restrict__ wk,
                                                     const float* __restrict__ wv, const float* __restrict__ wo,
                                                     u16* __restrict__ wt) {
  const int bid = blockIdx.x;                       // 1024 blocks: 4 weights x 256 tiles (64x64)
  const int widx = bid >> 8, tile = bid & 255, tr = tile >> 4, tc = tile & 15;
  const float* src = widx == 0 ? wq : widx == 1 ? wk : widx == 2 ? wv : wo;
  u16* dst = wt + (size_t)widx * 1048576;
  __shared__ float Ts[64 * 65];                     // +1 pad breaks bank conflicts
  const int t = threadIdx.x;
#pragma unroll
  for (int r = 0; r < 4; ++r) {
    int s = r * 256 + t;
    int row = s >> 4, c4 = (s & 15) * 4;
    float4 v = *(const float4*)(src + (size_t)(tr * 64 + row) * 1024 + tc * 64 + c4);
    Ts[row * 65 + c4 + 0] = v.x; Ts[row * 65 + c4 + 1] = v.y;
    Ts[row * 65 + c4 + 2] = v.z; Ts[row * 65 + c4 + 3] = v.w;
  }
  __syncthreads();
#pragma unroll
  for (int r = 0; r < 2; ++r) {
    int s = r * 256 + t;
    int rn = s >> 3, seg = s & 7;
    u16x8 ov;
#pragma unroll
    for (int j = 0; j < 8; ++j) ov[j] = f2bf(Ts[(seg * 8 + j) * 65 + rn]);
    *(u16x8*)(dst + (size_t)(tc * 64 + rn) * 1024 + tr * 64 + seg * 8) = ov;
  }
}

// ---------------- shared 128x128 GEMM core: C = A[128xK] * B^T-layout[128xK], K=1024 ----------------
__device__ __forceinline__ void gemm_core(const u16* __restrict__ A, const u16* __restrict__ B,
                                          u16* As, u16* Bs, f32x4 acc[4][4]) {
  const int t = threadIdx.x, lane = t & 63, w = t >> 6;
  const int wm = w >> 1, wn = w & 1;
  for (int kt = 0; kt < 16; ++kt) {
    __syncthreads();                                 // protect LDS reuse
#pragma unroll
    for (int r = 0; r < 4; ++r) {
      int s = r * 256 + t, row = s >> 3, gp = s & 7, seg = gp ^ (row & 7);
      gl_lds16(A + (size_t)row * 1024 + kt * 64 + seg * 8, As + (r * 256 + w * 64) * 8);
      gl_lds16(B + (size_t)row * 1024 + kt * 64 + seg * 8, Bs + (r * 256 + w * 64) * 8);
    }
    __syncthreads();                                 // drains vmcnt
#pragma unroll
    for (int ks = 0; ks < 2; ++ks) {
      bf16x8 af[4], bb[4];
#pragma unroll
      for (int i = 0; i < 4; ++i) {
        int rowA = wm * 64 + i * 16 + (lane & 15);
        int g = ks * 4 + (lane >> 4);
        af[i] = *(const bf16x8*)(As + rowA * 64 + ((g ^ (rowA & 7)) * 8));
        int rowB = wn * 64 + i * 16 + (lane & 15);
        bb[i] = *(const bf16x8*)(Bs + rowB * 64 + ((g ^ (rowB & 7)) * 8));
      }
      __builtin_amdgcn_s_setprio(1);
#pragma unroll
      for (int mi = 0; mi < 4; ++mi)
#pragma unroll
        for (int ni = 0; ni < 4; ++ni)
          acc[mi][ni] = __builtin_amdgcn_mfma_f32_16x16x32_bf16(af[mi], bb[ni], acc[mi][ni], 0, 0, 0);
      __builtin_amdgcn_s_setprio(0);
    }
  }
}

// ---------------- fused QKV projection ----------------
// Q gets 0.125*log2(e) folded in (softmax runs in log2 domain); V written transposed [d][s].
__global__ __launch_bounds__(256, 3) void qkv_gemm(const u16* __restrict__ xb, const u16* __restrict__ wt,
                                                   const float* __restrict__ bq, const float* __restrict__ bk,
                                                   const float* __restrict__ bv,
                                                   u16* __restrict__ Qb, u16* __restrict__ Kb, u16* __restrict__ Vt) {
  __shared__ u16 As[128 * 64], Bs[128 * 64];
  const int t = threadIdx.x, lane = t & 63, w = t >> 6;
  const int wm = w >> 1, wn = w & 1;
  const int mode = blockIdx.y >> 3;
  const int n0 = (blockIdx.y & 7) * 128;
  const int m0 = blockIdx.x * 128;
  f32x4 acc[4][4];
#pragma unroll
  for (int mi = 0; mi < 4; ++mi)
#pragma unroll
    for (int ni = 0; ni < 4; ++ni) acc[mi][ni] = (f32x4){0.f, 0.f, 0.f, 0.f};
  gemm_core(xb + (size_t)m0 * 1024, wt + (size_t)mode * 1048576 + (size_t)n0 * 1024, As, Bs, acc);
  const float* bias = mode == 0 ? bq : (mode == 1 ? bk : bv);
  const int row0 = m0 + wm * 64, col0 = n0 + wn * 64;
#pragma unroll
  for (int ni = 0; ni < 4; ++ni) {
    int col = col0 + ni * 16 + (lane & 15);
    float bv_ = bias[col];
#pragma unroll
    for (int mi = 0; mi < 4; ++mi) {
      int rb = row0 + mi * 16 + ((lane >> 4) << 2);
      if (mode == 0) {
#pragma unroll
        for (int r = 0; r < 4; ++r)
          ((__bf16*)Qb)[(size_t)(rb + r) * 1024 + col] = (__bf16)((acc[mi][ni][r] + bv_) * (0.125f * LOG2E));
      } else if (mode == 1) {
#pragma unroll
        for (int r = 0; r < 4; ++r)
          ((__bf16*)Kb)[(size_t)(rb + r) * 1024 + col] = (__bf16)(acc[mi][ni][r] + bv_);
      } else {
        bfx4 pk;                                     // 4 consecutive s at fixed (b,h,d): contiguous in Vt
#pragma unroll
        for (int r = 0; r < 4; ++r) pk[r] = (__bf16)(acc[mi][ni][r] + bv_);
        *(bfx4*)(Vt + (size_t)((rb >> 11) * 1024 + col) * 2048 + (rb & 2047)) = pk;
      }
    }
  }
}

// ---------------- causal flash attention ----------------
// Swapped QK^T (S^T = mfma(K,Q)) -> in-register softmax (q = lane&15 domain),
// l accumulated via ones-column MFMA (no explicit row-sum). 40KB LDS = 4 blocks/CU.
__global__ __launch_bounds__(256, 4) void attn_kernel(const u16* __restrict__ Qb, const u16* __restrict__ Kb,
                                                      const u16* __restrict__ Vt, u16* __restrict__ AO,
                                                      u16* __restrict__ POb, float* __restrict__ PML,
                                                      int CH, int LS, int QB0) {
  __shared__ u16 Ks[2][4096];                        // 16 KB K double-buffer
  __shared__ u16 Vs[4096];                           //  8 KB V^T tile [d][kv]
  __shared__ u16 Ps[4][2048];                        // 16 KB per-wave P, XOR-swizzled
  const int t = threadIdx.x, lane = t & 63, w = t >> 6;
  const int qhat = lane & 15, g = lane >> 4;
  const int bh = blockIdx.y;
  const int qb = blockIdx.x >> LS, c = blockIdx.x & ((1 << LS) - 1);
  const int totalt = 2 * qb + 2;
  const int nch = (totalt + CH - 1) / CH;
  if (c >= nch) return;
  const int t0 = c * CH;
  const int tend = (totalt < t0 + CH) ? totalt : (t0 + CH);
  const bool multi = nch > 1;

  const int qw = qb * 128 + w * 32;
  const size_t rowoff = (size_t)(bh >> 4) * 2048 * 1024 + (size_t)(bh & 15) * 64;
  const u16* Qp = Qb + rowoff;
  const u16* Kp = Kb + rowoff;
  const u16* Vp = Vt + (size_t)bh * 64 * 2048;
  u16* Pw = Ps[w];

  // ones B-fragment: virtual all-ones d-row (row index 0 of its 16-row group)
  bf16x8 vone;
  {
    short one = (qhat == 0) ? (short)0x3F80 : (short)0;
#pragma unroll
    for (int j = 0; j < 8; ++j) vone[j] = one;
  }

  // Q fragments straight from global (B-operand of swapped QK^T; same frag layout)
  bf16x8 aq[2][2];
#pragma unroll
  for (int ni = 0; ni < 2; ++ni)
#pragma unroll
    for (int ks = 0; ks < 2; ++ks)
      aq[ni][ks] = *(const bf16x8*)(Qp + (size_t)(qw + ni * 16 + qhat) * 1024 + (ks * 4 + g) * 8);

  f32x4 o[2][4];
  f32x4 ol[2];                                       // l accumulator (col 0 of ones-MFMA)
  float mrow[2];
#pragma unroll
  for (int mi = 0; mi < 2; ++mi) {
#pragma unroll
    for (int ni = 0; ni < 4; ++ni) o[mi][ni] = (f32x4){0.f, 0.f, 0.f, 0.f};
    ol[mi] = (f32x4){0.f, 0.f, 0.f, 0.f};
  }
  mrow[0] = NEGINF; mrow[1] = NEGINF;

#define STAGE_K_(BUF, KV0)                                                          \
  { _Pragma("unroll") for (int r_ = 0; r_ < 2; ++r_) {                              \
      int s_ = r_ * 256 + t, row_ = s_ >> 3, gp_ = s_ & 7, seg_ = gp_ ^ (row_ & 7); \
      gl_lds16(Kp + (size_t)((KV0) + row_) * 1024 + seg_ * 8,                       \
               &Ks[BUF][(r_ * 256 + w * 64) * 8]); } }
#define STAGE_V_(KV0)                                                               \
  { _Pragma("unroll") for (int r_ = 0; r_ < 2; ++r_) {                              \
      int s_ = r_ * 256 + t, row_ = s_ >> 3, gp_ = s_ & 7, seg_ = gp_ ^ (row_ & 7); \
      gl_lds16(Vp + (size_t)row_ * 2048 + (KV0) + seg_ * 8,                         \
               &Vs[(r_ * 256 + w * 64) * 8]); } }

  STAGE_K_(0, t0 * 64);
  __syncthreads();

  for (int kt = t0; kt < tend; ++kt) {
    const int buf = (kt - t0) & 1;
    const int kv0 = kt * 64;
    STAGE_V_(kv0);                                    // ready at mid-tile barrier
    if (kt + 1 < tend) STAGE_K_(buf ^ 1, kv0 + 64);   // prefetch next K
    const bool act = kv0 <= qw + 31;                  // wave-uniform skip

    if (act) {
      f32x4 sc[4][2];                                 // S^T: mi = k-tile, ni = q-tile
#pragma unroll
      for (int mi = 0; mi < 4; ++mi)
#pragma unroll
        for (int ni = 0; ni < 2; ++ni) sc[mi][ni] = (f32x4){0.f, 0.f, 0.f, 0.f};
#pragma unroll
      for (int ks = 0; ks < 2; ++ks) {
        bf16x8 kf[4];
#pragma unroll
        for (int mi = 0; mi < 4; ++mi) {
          int row = mi * 16 + qhat, gg = ks * 4 + g;
          kf[mi] = *(const bf16x8*)(&Ks[buf][row * 64 + ((gg ^ (row & 7)) * 8)]);
        }
        __builtin_amdgcn_s_setprio(1);
#pragma unroll
        for (int mi = 0; mi < 4; ++mi)
#pragma unroll
          for (int ni = 0; ni < 2; ++ni)
            sc[mi][ni] = __builtin_amdgcn_mfma_f32_16x16x32_bf16(kf[mi], aq[ni][ks], sc[mi][ni], 0, 0, 0);
        __builtin_amdgcn_s_setprio(0);
      }
      // causal mask: k = kv0+mi*16+g*4+r, q = qw+ni*16+qhat
      if (kv0 + 63 > qw) {
#pragma unroll
        for (int mi = 0; mi < 4; ++mi)
#pragma unroll
          for (int ni = 0; ni < 2; ++ni) {
            int qg = qw + ni * 16 + qhat;
#pragma unroll
            for (int r = 0; r < 4; ++r)
              if (kv0 + mi * 16 + g * 4 + r > qg) sc[mi][ni][r] = NEGINF;
          }
      }
      // row max: in-lane tree over 16 values, then xor16 + xor32
      float cm[2];
#pragma unroll
      for (int ni = 0; ni < 2; ++ni) {
        float a0 = fmaxf(fmaxf(sc[0][ni][0], sc[0][ni][1]), fmaxf(sc[0][ni][2], sc[0][ni][3]));
        float a1 = fmaxf(fmaxf(sc[1][ni][0], sc[1][ni][1]), fmaxf(sc[1][ni][2], sc[1][ni][3]));
        float a2 = fmaxf(fmaxf(sc[2][ni][0], sc[2][ni][1]), fmaxf(sc[2][ni][2], sc[2][ni][3]));
        float a3 = fmaxf(fmaxf(sc[3][ni][0], sc[3][ni][1]), fmaxf(sc[3][ni][2], sc[3][ni][3]));
        float m_ = fmaxf(fmaxf(a0, a1), fmaxf(a2, a3));
        m_ = fmaxf(m_, __shfl_xor(m_, 16));
        cm[ni] = fmaxf(m_, __shfl_xor(m_, 32));
      }
      // defer-max rescale (O and l-accumulator together)
      bool need = (cm[0] > mrow[0] + RESCALE_THR) || (cm[1] > mrow[1] + RESCALE_THR);
      if (__any(need)) {
        float al[2];
#pragma unroll
        for (int ni = 0; ni < 2; ++ni) {
          float mn = fmaxf(mrow[ni], cm[ni]);
          al[ni] = fast_exp2(mrow[ni] - mn);
          mrow[ni] = mn;
        }
        // redistribute al (q=lane&15 domain) to O rows (q=g*4+r domain)
        float a0v[4], a1v[4];
#pragma unroll
        for (int r = 0; r < 4; ++r) {
          int src = g * 4 + r;
          a0v[r] = __shfl(al[0], src);
          a1v[r] = __shfl(al[1], src);
        }
#pragma unroll
        for (int mi = 0; mi < 2; ++mi)
#pragma unroll
          for (int r = 0; r < 4; ++r) {
            float a_ = mi ? a1v[r] : a0v[r];
#pragma unroll
            for (int ni = 0; ni < 4; ++ni) o[mi][ni][r] *= a_;
            ol[mi][r] *= a_;
          }
      }
      // P = exp2(S - m) -> pack bf16 (v_cvt_pk) -> LDS (per-wave region)
#pragma unroll
      for (int mi = 0; mi < 4; ++mi)
#pragma unroll
        for (int ni = 0; ni < 2; ++ni) {
          bfx4 pk;
#pragma unroll
          for (int r = 0; r < 4; ++r) pk[r] = (__bf16)fast_exp2(sc[mi][ni][r] - mrow[ni]);
          int idx = (ni * 16 + qhat) * 64 + mi * 16 + g * 4;
          *(bfx4*)(Pw + (idx ^ ((qhat & 7) << 3))) = pk;
        }
    }
    __syncthreads();                                   // Vs ready (drains vmcnt)
    if (act) {
#pragma unroll
      for (int ks = 0; ks < 2; ++ks) {
        bf16x8 ap[2], vf[4];
#pragma unroll
        for (int mi = 0; mi < 2; ++mi) {
          int idx = (mi * 16 + qhat) * 64 + ks * 32 + g * 8;
          ap[mi] = *(const bf16x8*)(Pw + (idx ^ ((qhat & 7) << 3)));
        }
#pragma unroll
        for (int ni = 0; ni < 4; ++ni) {
          int row = ni * 16 + qhat, gg = ks * 4 + g;
          vf[ni] = *(const bf16x8*)(&Vs[row * 64 + ((gg ^ (row & 7)) * 8)]);
        }
        __builtin_amdgcn_s_setprio(1);
#pragma unroll
        for (int mi = 0; mi < 2; ++mi) {
          ol[mi] = __builtin_amdgcn_mfma_f32_16x16x32_bf16(ap[mi], vone, ol[mi], 0, 0, 0);
#pragma unroll
          for (int ni = 0; ni < 4; ++ni)
            o[mi][ni] = __builtin_amdgcn_mfma_f32_16x16x32_bf16(ap[mi], vf[ni], o[mi][ni], 0, 0, 0);
        }
        __builtin_amdgcn_s_setprio(0);
      }
    }
    __syncthreads();                                   // protect Vs/Ks reuse next iter
  }

  if (multi) {
    const int slot = ((bh * (16 - QB0) + (qb - QB0)) << LS) + c;
    __bf16* Po = (__bf16*)(POb + (size_t)slot * 8192); // [128][64] bf16 unnormalized partial
#pragma unroll
    for (int mi = 0; mi < 2; ++mi)
#pragma unroll
      for (int ni = 0; ni < 4; ++ni)
#pragma unroll
        for (int r = 0; r < 4; ++r)
          Po[(w * 32 + mi * 16 + g * 4 + r) * 64 + ni * 16 + qhat] = (__bf16)o[mi][ni][r];
    float* Pml = PML + (size_t)slot * 256;
    if (g == 0) {
#pragma unroll
      for (int ni = 0; ni < 2; ++ni)
        Pml[(w * 32 + ni * 16 + qhat) * 2] = mrow[ni];
    }
    if (qhat == 0) {
#pragma unroll
      for (int mi = 0; mi < 2; ++mi)
#pragma unroll
        for (int r = 0; r < 4; ++r)
          Pml[(w * 32 + mi * 16 + g * 4 + r) * 2 + 1] = ol[mi][r];
    }
  } else {
    // l lives in lanes qhat==0 (col 0 of ones-MFMA), rows = mi*16+g*4+r
    float il[2][4];
#pragma unroll
    for (int mi = 0; mi < 2; ++mi)
#pragma unroll
      for (int r = 0; r < 4; ++r)
        il[mi][r] = 1.0f / __shfl(ol[mi][r], g << 4);
    __bf16* Op = (__bf16*)(AO + rowoff);
#pragma unroll
    for (int mi = 0; mi < 2; ++mi)
#pragma unroll
      for (int ni = 0; ni < 4; ++ni)
#pragma unroll
        for (int r = 0; r < 4; ++r) {
          int row = qw + mi * 16 + g * 4 + r;
          Op[(size_t)row * 1024 + ni * 16 + qhat] = (__bf16)(o[mi][ni][r] * il[mi][r]);
        }
  }
#undef STAGE_K_
#undef STAGE_V_
}

// ---------------- merge KV-chunk partials ----------------
__global__ __launch_bounds__(256) void merge_kernel(const u16* __restrict__ POb, const float* __restrict__ PML,
                                                    u16* __restrict__ AO, int CH, int LS, int QB0) {
  const int qi = blockIdx.x, bh = blockIdx.y, t = threadIdx.x;
  const int qb = QB0 + qi;
  const int n = (2 * qb + 2 + CH - 1) / CH;
  if (n < 2) return;
  const int row = t >> 1, half = t & 1;
  const int s0 = (bh * (16 - QB0) + qi) << LS;
  float m[4], l[4];
  float M = NEGINF;
#pragma unroll 4
  for (int c = 0; c < n; ++c) {
    m[c] = PML[(size_t)(s0 + c) * 256 + row * 2];
    l[c] = PML[(size_t)(s0 + c) * 256 + row * 2 + 1];
    M = fmaxf(M, m[c]);
  }
  float D = 0.f, wgt[4];
#pragma unroll 4
  for (int c = 0; c < n; ++c) { wgt[c] = fast_exp2(m[c] - M); D += wgt[c] * l[c]; }
  float invD = 1.0f / D;
  float acc[32];
#pragma unroll
  for (int j = 0; j < 32; ++j) acc[j] = 0.f;
#pragma unroll 4
  for (int c = 0; c < n; ++c) {
    float coef = wgt[c] * invD;
    const u16* Po = POb + (size_t)(s0 + c) * 8192 + row * 64 + half * 32;
#pragma unroll
    for (int j4 = 0; j4 < 4; ++j4) {
      u16x8 v = *(const u16x8*)(Po + j4 * 8);
#pragma unroll
      for (int j = 0; j < 8; ++j) acc[j4 * 8 + j] += bf2f(v[j]) * coef;
    }
  }
  __bf16* Op = (__bf16*)(AO + (size_t)(bh >> 4) * 2048 * 1024 + (size_t)(bh & 15) * 64 +
                         (size_t)(qb * 128 + row) * 1024 + half * 32);
#pragma unroll
  for (int j4 = 0; j4 < 4; ++j4) {
    bfx4 ov0, ov1;
#pragma unroll
    for (int j = 0; j < 4; ++j) { ov0[j] = (__bf16)acc[j4 * 8 + j]; }
#pragma unroll
    for (int j = 0; j < 4; ++j) { ov1[j] = (__bf16)acc[j4 * 8 + 4 + j]; }
    *(bfx4*)(Op + j4 * 8) = ov0;
    *(bfx4*)(Op + j4 * 8 + 4) = ov1;
  }
}

// ---------------- output projection: out = AO @ Wo (fp32 out) ----------------
__global__ __launch_bounds__(256, 3) void out_gemm(const u16* __restrict__ AO, const u16* __restrict__ wot,
                                                   float* __restrict__ out) {
  __shared__ u16 As[128 * 64], Bs[128 * 64];
  const int t = threadIdx.x, lane = t & 63, w = t >> 6;
  const int wm = w >> 1, wn = w & 1;
  const int m0 = blockIdx.x * 128, n0 = blockIdx.y * 128;
  f32x4 acc[4][4];
#pragma unroll
  for (int mi = 0; mi < 4; ++mi)
#pragma unroll
    for (int ni = 0; ni < 4; ++ni) acc[mi][ni] = (f32x4){0.f, 0.f, 0.f, 0.f};
  gemm_core(AO + (size_t)m0 * 1024, wot + (size_t)n0 * 1024, As, Bs, acc);
  const int row0 = m0 + wm * 64, col0 = n0 + wn * 64;
#pragma unroll
  for (int ni = 0; ni < 4; ++ni) {
    int col = col0 + ni * 16 + (lane & 15);
#pragma unroll
    for (int mi = 0; mi < 4; ++mi) {
      int rb = row0 + mi * 16 + ((lane >> 4) << 2);
#pragma unroll
      for (int r = 0; r < 4; ++r)
        out[(size_t)(rb + r) * 1024 + col] = acc[mi][ni][r];
    }
  }
}

extern "C" void kernel_launch(void* const* d_in, const int* in_sizes, int n_in,
                              void* d_out, int out_size, void* d_ws, size_t ws_size,
                              hipStream_t stream) {
  const float* x  = (const float*)d_in[0];
  const float* Wq = (const float*)d_in[1];
  const float* bq = (const float*)d_in[2];
  const float* Wk = (const float*)d_in[3];
  const float* bk = (const float*)d_in[4];
  const float* Wv = (const float*)d_in[5];
  const float* bv = (const float*)d_in[6];
  const float* Wo = (const float*)d_in[7];
  float* out = (float*)d_out;

  char* ws = (char*)d_ws;
  u16* xb = (u16*)(ws);                               //  8 MB  x as bf16 [4096][1024]
  u16* wt = (u16*)(ws + (size_t)8  * 1048576);        //  8 MB  Wq^T,Wk^T,Wv^T,Wo^T bf16
  u16* Qb = (u16*)(ws + (size_t)16 * 1048576);        //  8 MB  Q (pre-scaled 0.125*log2e)
  u16* Kb = (u16*)(ws + (size_t)24 * 1048576);        //  8 MB  K
  u16* Vt = (u16*)(ws + (size_t)32 * 1048576);        //  8 MB  V transposed [B*H][64][2048]
  u16* AO = (u16*)(ws + (size_t)40 * 1048576);        //  8 MB  attention out [4096][1024]
  const size_t base = (size_t)48 * 1048576;

  // chunking mode: CH=8 (4 chunks, QB0=4) -> CH=16 (2 chunks, QB0=8) -> unchunked
  int CH, LS, QB0;
  size_t slots;
  const size_t slots8 = 32 * 12 * 4, slots16 = 32 * 8 * 2;
  const size_t need8  = base + slots8  * (8192 * 2 + 256 * 4);
  const size_t need16 = base + slots16 * (8192 * 2 + 256 * 4);
  if (ws_size >= need8)       { CH = 8;    LS = 2; QB0 = 4;  slots = slots8;  }
  else if (ws_size >= need16) { CH = 16;   LS = 1; QB0 = 8;  slots = slots16; }
  else                        { CH = 4096; LS = 0; QB0 = 16; slots = 0;       }
  u16* POb = (u16*)(ws + base);
  float* PML = (float*)(ws + base + slots * 8192 * 2);

  conv_x_kernel<<<dim3(4096), dim3(256), 0, stream>>>(x, xb);
  conv_w_kernel<<<dim3(1024), dim3(256), 0, stream>>>(Wq, Wk, Wv, Wo, wt);
  qkv_gemm<<<dim3(32, 24), dim3(256), 0, stream>>>(xb, wt, bq, bk, bv, Qb, Kb, Vt);
  attn_kernel<<<dim3(16 << LS, 32), dim3(256), 0, stream>>>(Qb, Kb, Vt, AO, POb, PML, CH, LS, QB0);
  if (QB0 < 16) merge_kernel<<<dim3(16 - QB0, 32), dim3(256), 0, stream>>>(POb, PML, AO, CH, LS, QB0);
  out_gemm<<<dim3(32, 8), dim3(256), 0, stream>>>(AO, wt + (size_t)3 * 1048576, out);
}

// Round 5
// 195.144 us; speedup vs baseline: 1.3272x; 1.3272x over previous
//
#include <hip/hip_runtime.h>
#include <hip/hip_bf16.h>
#include <cstdint>
#include <cstddef>

typedef unsigned short u16;
typedef __attribute__((ext_vector_type(8))) short bf16x8;   // 8 bf16 = 4 VGPRs (MFMA A/B frag)
typedef __attribute__((ext_vector_type(4))) float f32x4;    // MFMA C/D frag
typedef __attribute__((ext_vector_type(4))) u16 u16x4;
typedef __attribute__((ext_vector_type(8))) u16 u16x8;
typedef __attribute__((ext_vector_type(4))) __bf16 bfx4;    // 4 native bf16 -> 2 v_cvt_pk_bf16_f32

#define AS1 __attribute__((address_space(1)))
#define AS3 __attribute__((address_space(3)))

// async global->LDS, 16B per lane; LDS dest must be wave-uniform base + lane*16
__device__ __forceinline__ void gl_lds16(const void* g, void* l) {
  __builtin_amdgcn_global_load_lds((const AS1 unsigned int*)g, (AS3 unsigned int*)l, 16, 0, 0);
}

__device__ __forceinline__ u16 f2bf(float f) {  // round-to-nearest-even bf16 (cold paths)
  union { float f; unsigned u; } v; v.f = f;
  unsigned r = v.u + 0x7FFFu + ((v.u >> 16) & 1u);
  return (u16)(r >> 16);
}

__device__ __forceinline__ float bf2f(u16 b) {
  union { float f; unsigned u; } v; v.u = ((unsigned)b) << 16; return v.f;
}

__device__ __forceinline__ float fast_exp2(float x) {  // v_exp_f32 = exact hw exp2
  float r; asm("v_exp_f32 %0, %1" : "=v"(r) : "v"(x)); return r;
}

#define NEGINF (-__builtin_inff())
#define LOG2E 1.44269504088896340736f
#define RESCALE_THR 7.0f

// ---------------- fp32 -> bf16 convert (x) ----------------
__global__ __launch_bounds__(256) void conv_x_kernel(const float* __restrict__ x, u16* __restrict__ xb) {
  int i = blockIdx.x * 256 + threadIdx.x;   // 1M threads, 4 elements each
  float4 v = ((const float4*)x)[i];
  u16x4 o;
  o[0] = f2bf(v.x); o[1] = f2bf(v.y); o[2] = f2bf(v.z); o[3] = f2bf(v.w);
  ((u16x4*)xb)[i] = o;
}

// -------- weight transpose+convert: W[K][N] f32 -> Wt[N][K] bf16 (4 weights) --------
__global__ __launch_bounds__(256) void conv_w_kernel(const float* __restrict__ wq, const float* __restrict__ wk,
                                                     const float* __restrict__ wv, const float* __restrict__ wo,
                                                     u16* __restrict__ wt) {
  const int bid = blockIdx.x;                       // 1024 blocks: 4 weights x 256 tiles (64x64)
  const int widx = bid >> 8, tile = bid & 255, tr = tile >> 4, tc = tile & 15;
  const float* src = widx == 0 ? wq : widx == 1 ? wk : widx == 2 ? wv : wo;
  u16* dst = wt + (size_t)widx * 1048576;
  __shared__ float Ts[64 * 65];                     // +1 pad breaks bank conflicts
  const int t = threadIdx.x;
#pragma unroll
  for (int r = 0; r < 4; ++r) {
    int s = r * 256 + t;
    int row = s >> 4, c4 = (s & 15) * 4;
    float4 v = *(const float4*)(src + (size_t)(tr * 64 + row) * 1024 + tc * 64 + c4);
    Ts[row * 65 + c4 + 0] = v.x; Ts[row * 65 + c4 + 1] = v.y;
    Ts[row * 65 + c4 + 2] = v.z; Ts[row * 65 + c4 + 3] = v.w;
  }
  __syncthreads();
#pragma unroll
  for (int r = 0; r < 2; ++r) {
    int s = r * 256 + t;
    int rn = s >> 3, seg = s & 7;
    u16x8 ov;
#pragma unroll
    for (int j = 0; j < 8; ++j) ov[j] = f2bf(Ts[(seg * 8 + j) * 65 + rn]);
    *(u16x8*)(dst + (size_t)(tc * 64 + rn) * 1024 + tr * 64 + seg * 8) = ov;
  }
}

// ---------------- shared 128x128 GEMM core: C = A[128xK] * B^T-layout[128xK], K=1024 ----------------
__device__ __forceinline__ void gemm_core(const u16* __restrict__ A, const u16* __restrict__ B,
                                          u16* As, u16* Bs, f32x4 acc[4][4]) {
  const int t = threadIdx.x, lane = t & 63, w = t >> 6;
  const int wm = w >> 1, wn = w & 1;
  for (int kt = 0; kt < 16; ++kt) {
    __syncthreads();                                 // protect LDS reuse
#pragma unroll
    for (int r = 0; r < 4; ++r) {
      int s = r * 256 + t, row = s >> 3, gp = s & 7, seg = gp ^ (row & 7);
      gl_lds16(A + (size_t)row * 1024 + kt * 64 + seg * 8, As + (r * 256 + w * 64) * 8);
      gl_lds16(B + (size_t)row * 1024 + kt * 64 + seg * 8, Bs + (r * 256 + w * 64) * 8);
    }
    __syncthreads();                                 // drains vmcnt
#pragma unroll
    for (int ks = 0; ks < 2; ++ks) {
      bf16x8 af[4], bb[4];
#pragma unroll
      for (int i = 0; i < 4; ++i) {
        int rowA = wm * 64 + i * 16 + (lane & 15);
        int g = ks * 4 + (lane >> 4);
        af[i] = *(const bf16x8*)(As + rowA * 64 + ((g ^ (rowA & 7)) * 8));
        int rowB = wn * 64 + i * 16 + (lane & 15);
        bb[i] = *(const bf16x8*)(Bs + rowB * 64 + ((g ^ (rowB & 7)) * 8));
      }
#pragma unroll
      for (int mi = 0; mi < 4; ++mi)
#pragma unroll
        for (int ni = 0; ni < 4; ++ni)
          acc[mi][ni] = __builtin_amdgcn_mfma_f32_16x16x32_bf16(af[mi], bb[ni], acc[mi][ni], 0, 0, 0);
    }
  }
}

// ---------------- fused QKV projection ----------------
// Q gets 0.125*log2(e) folded in (softmax runs in log2 domain); V written transposed [d][s].
__global__ __launch_bounds__(256, 2) void qkv_gemm(const u16* __restrict__ xb, const u16* __restrict__ wt,
                                                   const float* __restrict__ bq, const float* __restrict__ bk,
                                                   const float* __restrict__ bv,
                                                   u16* __restrict__ Qb, u16* __restrict__ Kb, u16* __restrict__ Vt) {
  __shared__ u16 As[128 * 64], Bs[128 * 64];
  const int t = threadIdx.x, lane = t & 63, w = t >> 6;
  const int wm = w >> 1, wn = w & 1;
  const int mode = blockIdx.y >> 3;
  const int n0 = (blockIdx.y & 7) * 128;
  const int m0 = blockIdx.x * 128;
  f32x4 acc[4][4];
#pragma unroll
  for (int mi = 0; mi < 4; ++mi)
#pragma unroll
    for (int ni = 0; ni < 4; ++ni) acc[mi][ni] = (f32x4){0.f, 0.f, 0.f, 0.f};
  gemm_core(xb + (size_t)m0 * 1024, wt + (size_t)mode * 1048576 + (size_t)n0 * 1024, As, Bs, acc);
  const float* bias = mode == 0 ? bq : (mode == 1 ? bk : bv);
  const int row0 = m0 + wm * 64, col0 = n0 + wn * 64;
#pragma unroll
  for (int ni = 0; ni < 4; ++ni) {
    int col = col0 + ni * 16 + (lane & 15);
    float bv_ = bias[col];
#pragma unroll
    for (int mi = 0; mi < 4; ++mi) {
      int rb = row0 + mi * 16 + ((lane >> 4) << 2);
      if (mode == 0) {
#pragma unroll
        for (int r = 0; r < 4; ++r)
          ((__bf16*)Qb)[(size_t)(rb + r) * 1024 + col] = (__bf16)((acc[mi][ni][r] + bv_) * (0.125f * LOG2E));
      } else if (mode == 1) {
#pragma unroll
        for (int r = 0; r < 4; ++r)
          ((__bf16*)Kb)[(size_t)(rb + r) * 1024 + col] = (__bf16)(acc[mi][ni][r] + bv_);
      } else {
        bfx4 pk;                                     // 4 consecutive s at fixed (b,h,d): contiguous in Vt
#pragma unroll
        for (int r = 0; r < 4; ++r) pk[r] = (__bf16)(acc[mi][ni][r] + bv_);
        *(bfx4*)(Vt + (size_t)((rb >> 11) * 1024 + col) * 2048 + (rb & 2047)) = pk;
      }
    }
  }
}

// ---------------- causal flash attention ----------------
// Swapped QK^T (S^T = mfma(K,Q)) -> in-register softmax (q = lane&15 domain).
// K AND V double-buffered; next tile's K+V issued BEFORE current compute;
// ONE barrier per tile (its vmcnt drain covers loads that flew under compute).
// XCD-bijective block swizzle: 4 consecutive bh per XCD -> K/V L2-resident.
// LDS 48KB -> 3 blocks/CU.
__global__ __launch_bounds__(256, 3) void attn_kernel(const u16* __restrict__ Qb, const u16* __restrict__ Kb,
                                                      const u16* __restrict__ Vt, u16* __restrict__ AO,
                                                      u16* __restrict__ POb, float* __restrict__ PML,
                                                      int CH, int LS, int QB0) {
  __shared__ u16 Ks[2][4096];                        // 16 KB K double-buffer
  __shared__ u16 Vs[2][4096];                        // 16 KB V^T double-buffer [d][kv]
  __shared__ u16 Ps[4][2048];                        // 16 KB per-wave P, XOR-swizzled
  const int t = threadIdx.x, lane = t & 63, w = t >> 6;
  const int qhat = lane & 15, g = lane >> 4;
  // XCD-aware bijective swizzle (total = 32<<(4+LS), divisible by 8)
  const int shift = 4 + LS;
  const int lin = blockIdx.y * (1 << shift) + blockIdx.x;
  const int nid = (lin & 7) * (4 << shift) + (lin >> 3);
  const int bh = nid >> shift;
  const int item = nid & ((1 << shift) - 1);
  const int qb = item >> LS, c = item & ((1 << LS) - 1);
  const int totalt = 2 * qb + 2;
  const int nch = (totalt + CH - 1) / CH;
  if (c >= nch) return;
  const int t0 = c * CH;
  const int tend = (totalt < t0 + CH) ? totalt : (t0 + CH);
  const bool multi = nch > 1;

  const int qw = qb * 128 + w * 32;
  const size_t rowoff = (size_t)(bh >> 4) * 2048 * 1024 + (size_t)(bh & 15) * 64;
  const u16* Qp = Qb + rowoff;
  const u16* Kp = Kb + rowoff;
  const u16* Vp = Vt + (size_t)bh * 64 * 2048;
  u16* Pw = Ps[w];

  // Q fragments straight from global (B-operand of swapped QK^T; same frag layout)
  bf16x8 aq[2][2];
#pragma unroll
  for (int ni = 0; ni < 2; ++ni)
#pragma unroll
    for (int ks = 0; ks < 2; ++ks)
      aq[ni][ks] = *(const bf16x8*)(Qp + (size_t)(qw + ni * 16 + qhat) * 1024 + (ks * 4 + g) * 8);

  f32x4 o[2][4];
  float mrow[2], lrow[2];
#pragma unroll
  for (int mi = 0; mi < 2; ++mi)
#pragma unroll
    for (int ni = 0; ni < 4; ++ni) o[mi][ni] = (f32x4){0.f, 0.f, 0.f, 0.f};
  mrow[0] = NEGINF; mrow[1] = NEGINF; lrow[0] = 0.f; lrow[1] = 0.f;

#define STAGE_KV_(BUF, KV0)                                                         \
  { _Pragma("unroll") for (int r_ = 0; r_ < 2; ++r_) {                              \
      int s_ = r_ * 256 + t, row_ = s_ >> 3, gp_ = s_ & 7, seg_ = gp_ ^ (row_ & 7); \
      gl_lds16(Kp + (size_t)((KV0) + row_) * 1024 + seg_ * 8,                       \
               &Ks[BUF][(r_ * 256 + w * 64) * 8]);                                  \
      gl_lds16(Vp + (size_t)row_ * 2048 + (KV0) + seg_ * 8,                         \
               &Vs[BUF][(r_ * 256 + w * 64) * 8]); } }

  STAGE_KV_(0, t0 * 64);
  __syncthreads();                                   // first tile landed

  for (int kt = t0; kt < tend; ++kt) {
    const int buf = (kt - t0) & 1;
    const int kv0 = kt * 64;
    if (kt + 1 < tend) STAGE_KV_(buf ^ 1, kv0 + 64); // issue next tile FIRST (flies under compute)
    const bool act = kv0 <= qw + 31;                 // wave-uniform skip

    if (act) {
      f32x4 sc[4][2];                                // S^T: mi = k-tile, ni = q-tile
#pragma unroll
      for (int mi = 0; mi < 4; ++mi)
#pragma unroll
        for (int ni = 0; ni < 2; ++ni) sc[mi][ni] = (f32x4){0.f, 0.f, 0.f, 0.f};
#pragma unroll
      for (int ks = 0; ks < 2; ++ks) {
        bf16x8 kf[4];
#pragma unroll
        for (int mi = 0; mi < 4; ++mi) {
          int row = mi * 16 + qhat, gg = ks * 4 + g;
          kf[mi] = *(const bf16x8*)(&Ks[buf][row * 64 + ((gg ^ (row & 7)) * 8)]);
        }
#pragma unroll
        for (int mi = 0; mi < 4; ++mi)
#pragma unroll
          for (int ni = 0; ni < 2; ++ni)
            sc[mi][ni] = __builtin_amdgcn_mfma_f32_16x16x32_bf16(kf[mi], aq[ni][ks], sc[mi][ni], 0, 0, 0);
      }
      // causal mask: k = kv0+mi*16+g*4+r, q = qw+ni*16+qhat
      if (kv0 + 63 > qw) {
#pragma unroll
        for (int mi = 0; mi < 4; ++mi)
#pragma unroll
          for (int ni = 0; ni < 2; ++ni) {
            int qg = qw + ni * 16 + qhat;
#pragma unroll
            for (int r = 0; r < 4; ++r)
              if (kv0 + mi * 16 + g * 4 + r > qg) sc[mi][ni][r] = NEGINF;
          }
      }
      // row max: in-lane tree over 16 values, then xor16 + xor32
      float cm[2];
#pragma unroll
      for (int ni = 0; ni < 2; ++ni) {
        float a0 = fmaxf(fmaxf(sc[0][ni][0], sc[0][ni][1]), fmaxf(sc[0][ni][2], sc[0][ni][3]));
        float a1 = fmaxf(fmaxf(sc[1][ni][0], sc[1][ni][1]), fmaxf(sc[1][ni][2], sc[1][ni][3]));
        float a2 = fmaxf(fmaxf(sc[2][ni][0], sc[2][ni][1]), fmaxf(sc[2][ni][2], sc[2][ni][3]));
        float a3 = fmaxf(fmaxf(sc[3][ni][0], sc[3][ni][1]), fmaxf(sc[3][ni][2], sc[3][ni][3]));
        float m_ = fmaxf(fmaxf(a0, a1), fmaxf(a2, a3));
        m_ = fmaxf(m_, __shfl_xor(m_, 16));
        cm[ni] = fmaxf(m_, __shfl_xor(m_, 32));
      }
      // defer-max rescale
      bool need = (cm[0] > mrow[0] + RESCALE_THR) || (cm[1] > mrow[1] + RESCALE_THR);
      if (__any(need)) {
        float al[2];
#pragma unroll
        for (int ni = 0; ni < 2; ++ni) {
          float mn = fmaxf(mrow[ni], cm[ni]);
          al[ni] = fast_exp2(mrow[ni] - mn);
          mrow[ni] = mn;
          lrow[ni] *= al[ni];
        }
        // redistribute al (q=lane&15 domain) to O rows (q=g*4+r domain)
        float a0v[4], a1v[4];
#pragma unroll
        for (int r = 0; r < 4; ++r) {
          int src = g * 4 + r;
          a0v[r] = __shfl(al[0], src);
          a1v[r] = __shfl(al[1], src);
        }
#pragma unroll
        for (int mi = 0; mi < 2; ++mi)
#pragma unroll
          for (int ni = 0; ni < 4; ++ni)
#pragma unroll
            for (int r = 0; r < 4; ++r)
              o[mi][ni][r] *= (mi ? a1v[r] : a0v[r]);
      }
      // P = exp2(S - m): in-lane sums + xor16/xor32; pack via v_cvt_pk -> LDS
      float rs[2];
#pragma unroll
      for (int ni = 0; ni < 2; ++ni) {
        float s_ = 0.f;
#pragma unroll
        for (int mi = 0; mi < 4; ++mi) {
          float p0 = fast_exp2(sc[mi][ni][0] - mrow[ni]);
          float p1 = fast_exp2(sc[mi][ni][1] - mrow[ni]);
          float p2 = fast_exp2(sc[mi][ni][2] - mrow[ni]);
          float p3 = fast_exp2(sc[mi][ni][3] - mrow[ni]);
          sc[mi][ni][0] = p0; sc[mi][ni][1] = p1; sc[mi][ni][2] = p2; sc[mi][ni][3] = p3;
          s_ += (p0 + p1) + (p2 + p3);
        }
        s_ += __shfl_xor(s_, 16);
        rs[ni] = s_ + __shfl_xor(s_, 32);
        lrow[ni] += rs[ni];
      }
#pragma unroll
      for (int mi = 0; mi < 4; ++mi)
#pragma unroll
        for (int ni = 0; ni < 2; ++ni) {
          bfx4 pk;
#pragma unroll
          for (int r = 0; r < 4; ++r) pk[r] = (__bf16)sc[mi][ni][r];
          int idx = (ni * 16 + qhat) * 64 + mi * 16 + g * 4;
          *(bfx4*)(Pw + (idx ^ ((qhat & 7) << 3))) = pk;
        }
      // O += P V (P per-wave: no barrier needed; V staged last iteration)
#pragma unroll
      for (int ks = 0; ks < 2; ++ks) {
        bf16x8 ap[2], vf[4];
#pragma unroll
        for (int mi = 0; mi < 2; ++mi) {
          int idx = (mi * 16 + qhat) * 64 + ks * 32 + g * 8;
          ap[mi] = *(const bf16x8*)(Pw + (idx ^ ((qhat & 7) << 3)));
        }
#pragma unroll
        for (int ni = 0; ni < 4; ++ni) {
          int row = ni * 16 + qhat, gg = ks * 4 + g;
          vf[ni] = *(const bf16x8*)(&Vs[buf][row * 64 + ((gg ^ (row & 7)) * 8)]);
        }
#pragma unroll
        for (int mi = 0; mi < 2; ++mi)
#pragma unroll
          for (int ni = 0; ni < 4; ++ni)
            o[mi][ni] = __builtin_amdgcn_mfma_f32_16x16x32_bf16(ap[mi], vf[ni], o[mi][ni], 0, 0, 0);
      }
    }
    __syncthreads();                                 // next tile's K+V landed; bufs safe to swap
  }

  if (multi) {
    const int slot = ((bh * (16 - QB0) + (qb - QB0)) << LS) + c;
    __bf16* Po = (__bf16*)(POb + (size_t)slot * 8192); // [128][64] bf16 unnormalized partial
#pragma unroll
    for (int mi = 0; mi < 2; ++mi)
#pragma unroll
      for (int ni = 0; ni < 4; ++ni)
#pragma unroll
        for (int r = 0; r < 4; ++r)
          Po[(w * 32 + mi * 16 + g * 4 + r) * 64 + ni * 16 + qhat] = (__bf16)o[mi][ni][r];
    if (g == 0) {
      float* Pml = PML + (size_t)slot * 256;
#pragma unroll
      for (int ni = 0; ni < 2; ++ni) {
        int row = w * 32 + ni * 16 + qhat;
        Pml[row * 2 + 0] = mrow[ni];
        Pml[row * 2 + 1] = lrow[ni];
      }
    }
  } else {
    // redistribute 1/l to O domain, store normalized bf16
    float i0v[4], i1v[4];
#pragma unroll
    for (int r = 0; r < 4; ++r) {
      int src = g * 4 + r;
      i0v[r] = 1.0f / __shfl(lrow[0], src);
      i1v[r] = 1.0f / __shfl(lrow[1], src);
    }
    __bf16* Op = (__bf16*)(AO + rowoff);
#pragma unroll
    for (int mi = 0; mi < 2; ++mi)
#pragma unroll
      for (int ni = 0; ni < 4; ++ni)
#pragma unroll
        for (int r = 0; r < 4; ++r) {
          int row = qw + mi * 16 + g * 4 + r;
          Op[(size_t)row * 1024 + ni * 16 + qhat] = (__bf16)(o[mi][ni][r] * (mi ? i1v[r] : i0v[r]));
        }
  }
#undef STAGE_KV_
}

// ---------------- merge KV-chunk partials ----------------
__global__ __launch_bounds__(256) void merge_kernel(const u16* __restrict__ POb, const float* __restrict__ PML,
                                                    u16* __restrict__ AO, int CH, int LS, int QB0) {
  const int qi = blockIdx.x, bh = blockIdx.y, t = threadIdx.x;
  const int qb = QB0 + qi;
  const int n = (2 * qb + 2 + CH - 1) / CH;
  if (n < 2) return;
  const int row = t >> 1, half = t & 1;
  const int s0 = (bh * (16 - QB0) + qi) << LS;
  float m[4], l[4];
  float M = NEGINF;
#pragma unroll 4
  for (int c = 0; c < n; ++c) {
    m[c] = PML[(size_t)(s0 + c) * 256 + row * 2];
    l[c] = PML[(size_t)(s0 + c) * 256 + row * 2 + 1];
    M = fmaxf(M, m[c]);
  }
  float D = 0.f, wgt[4];
#pragma unroll 4
  for (int c = 0; c < n; ++c) { wgt[c] = fast_exp2(m[c] - M); D += wgt[c] * l[c]; }
  float invD = 1.0f / D;
  float acc[32];
#pragma unroll
  for (int j = 0; j < 32; ++j) acc[j] = 0.f;
#pragma unroll 4
  for (int c = 0; c < n; ++c) {
    float coef = wgt[c] * invD;
    const u16* Po = POb + (size_t)(s0 + c) * 8192 + row * 64 + half * 32;
#pragma unroll
    for (int j4 = 0; j4 < 4; ++j4) {
      u16x8 v = *(const u16x8*)(Po + j4 * 8);
#pragma unroll
      for (int j = 0; j < 8; ++j) acc[j4 * 8 + j] += bf2f(v[j]) * coef;
    }
  }
  __bf16* Op = (__bf16*)(AO + (size_t)(bh >> 4) * 2048 * 1024 + (size_t)(bh & 15) * 64 +
                         (size_t)(qb * 128 + row) * 1024 + half * 32);
#pragma unroll
  for (int j4 = 0; j4 < 4; ++j4) {
    bfx4 ov0, ov1;
#pragma unroll
    for (int j = 0; j < 4; ++j) { ov0[j] = (__bf16)acc[j4 * 8 + j]; }
#pragma unroll
    for (int j = 0; j < 4; ++j) { ov1[j] = (__bf16)acc[j4 * 8 + 4 + j]; }
    *(bfx4*)(Op + j4 * 8) = ov0;
    *(bfx4*)(Op + j4 * 8 + 4) = ov1;
  }
}

// ---------------- output projection: out = AO @ Wo (fp32 out) ----------------
__global__ __launch_bounds__(256, 2) void out_gemm(const u16* __restrict__ AO, const u16* __restrict__ wot,
                                                   float* __restrict__ out) {
  __shared__ u16 As[128 * 64], Bs[128 * 64];
  const int t = threadIdx.x, lane = t & 63, w = t >> 6;
  const int wm = w >> 1, wn = w & 1;
  const int m0 = blockIdx.x * 128, n0 = blockIdx.y * 128;
  f32x4 acc[4][4];
#pragma unroll
  for (int mi = 0; mi < 4; ++mi)
#pragma unroll
    for (int ni = 0; ni < 4; ++ni) acc[mi][ni] = (f32x4){0.f, 0.f, 0.f, 0.f};
  gemm_core(AO + (size_t)m0 * 1024, wot + (size_t)n0 * 1024, As, Bs, acc);
  const int row0 = m0 + wm * 64, col0 = n0 + wn * 64;
#pragma unroll
  for (int ni = 0; ni < 4; ++ni) {
    int col = col0 + ni * 16 + (lane & 15);
#pragma unroll
    for (int mi = 0; mi < 4; ++mi) {
      int rb = row0 + mi * 16 + ((lane >> 4) << 2);
#pragma unroll
      for (int r = 0; r < 4; ++r)
        out[(size_t)(rb + r) * 1024 + col] = acc[mi][ni][r];
    }
  }
}

extern "C" void kernel_launch(void* const* d_in, const int* in_sizes, int n_in,
                              void* d_out, int out_size, void* d_ws, size_t ws_size,
                              hipStream_t stream) {
  const float* x  = (const float*)d_in[0];
  const float* Wq = (const float*)d_in[1];
  const float* bq = (const float*)d_in[2];
  const float* Wk = (const float*)d_in[3];
  const float* bk = (const float*)d_in[4];
  const float* Wv = (const float*)d_in[5];
  const float* bv = (const float*)d_in[6];
  const float* Wo = (const float*)d_in[7];
  float* out = (float*)d_out;

  char* ws = (char*)d_ws;
  u16* xb = (u16*)(ws);                               //  8 MB  x as bf16 [4096][1024]
  u16* wt = (u16*)(ws + (size_t)8  * 1048576);        //  8 MB  Wq^T,Wk^T,Wv^T,Wo^T bf16
  u16* Qb = (u16*)(ws + (size_t)16 * 1048576);        //  8 MB  Q (pre-scaled 0.125*log2e)
  u16* Kb = (u16*)(ws + (size_t)24 * 1048576);        //  8 MB  K
  u16* Vt = (u16*)(ws + (size_t)32 * 1048576);        //  8 MB  V transposed [B*H][64][2048]
  u16* AO = (u16*)(ws + (size_t)40 * 1048576);        //  8 MB  attention out [4096][1024]
  const size_t base = (size_t)48 * 1048576;

  // chunking mode: CH=8 (4 chunks, QB0=4) -> CH=16 (2 chunks, QB0=8) -> unchunked
  int CH, LS, QB0;
  size_t slots;
  const size_t slots8 = 32 * 12 * 4, slots16 = 32 * 8 * 2;
  const size_t need8  = base + slots8  * (8192 * 2 + 256 * 4);
  const size_t need16 = base + slots16 * (8192 * 2 + 256 * 4);
  if (ws_size >= need8)       { CH = 8;    LS = 2; QB0 = 4;  slots = slots8;  }
  else if (ws_size >= need16) { CH = 16;   LS = 1; QB0 = 8;  slots = slots16; }
  else                        { CH = 4096; LS = 0; QB0 = 16; slots = 0;       }
  u16* POb = (u16*)(ws + base);
  float* PML = (float*)(ws + base + slots * 8192 * 2);

  conv_x_kernel<<<dim3(4096), dim3(256), 0, stream>>>(x, xb);
  conv_w_kernel<<<dim3(1024), dim3(256), 0, stream>>>(Wq, Wk, Wv, Wo, wt);
  qkv_gemm<<<dim3(32, 24), dim3(256), 0, stream>>>(xb, wt, bq, bk, bv, Qb, Kb, Vt);
  attn_kernel<<<dim3(16 << LS, 32), dim3(256), 0, stream>>>(Qb, Kb, Vt, AO, POb, PML, CH, LS, QB0);
  if (QB0 < 16) merge_kernel<<<dim3(16 - QB0, 32), dim3(256), 0, stream>>>(POb, PML, AO, CH, LS, QB0);
  out_gemm<<<dim3(32, 8), dim3(256), 0, stream>>>(AO, wt + (size_t)3 * 1048576, out);
}